// Round 4
// baseline (887.694 us; speedup 1.0000x reference)
//
#include <hip/hip_runtime.h>
#include <math.h>

// HMLSTMOutput — buffers are fp32 in AND fp32 out (reference dtypes; harness doc).
// Checker compares vs a bf16-computed np ref at 2% tol -> internal bf16 MFMA compute is fine.
// x[32768,1536] -> gates -> gated embed GEMM -> 2x tanh GEMM -> out GEMM (fp32 store).
// R2 failure signature (finite 0.646 = two packed bf16 read as one fp32) pinpointed the
// output store dtype as the sole bug; this round stores fp32. 2-chunk schedule keeps ws=88MB.

typedef __attribute__((ext_vector_type(8))) short short8;   // 8 bf16 = 4 VGPRs (MFMA A/B frag)
typedef __attribute__((ext_vector_type(4))) float float4v;  // MFMA C/D frag

#define DEV __device__ __forceinline__

DEV unsigned short f2bf(float f){
    union{float f; unsigned int i;} c; c.f = f;
    unsigned int r = c.i + 0x7fffu + ((c.i>>16)&1u);   // round-to-nearest-even
    return (unsigned short)(r>>16);
}
DEV unsigned int pack2(float a, float b){
    return (unsigned int)f2bf(a) | ((unsigned int)f2bf(b)<<16);
}

// -------- convert fp32 -> bf16, flat (W1, W2, Wo). 8 elems / thread ----------
__global__ __launch_bounds__(256) void cvt_flat(const float* __restrict__ src,
                                                unsigned short* __restrict__ dst, int n8)
{
    int v = blockIdx.x*256 + threadIdx.x;
    if(v >= n8) return;
    const float4* s = (const float4*)(src) + v*2;
    float4 a = s[0], b = s[1];
    uint4 o;
    o.x = pack2(a.x, a.y); o.y = pack2(a.z, a.w);
    o.z = pack2(b.x, b.y); o.w = pack2(b.z, b.w);
    *((uint4*)dst + v) = o;
}

// -------- We [3,1024,512] fp32 -> Wep [1024,1536] bf16 (repack + convert) -------
__global__ __launch_bounds__(256) void cvt_we(const float* __restrict__ We,
                                              unsigned short* __restrict__ Wep)
{
    int v  = blockIdx.x*256 + threadIdx.x;   // 196608 vectors of 8 elems
    int i8 = v & 63;
    int e  = (v>>6) & 1023;
    int l  = v>>16;
    const float4* s = (const float4*)(We + (size_t)l*524288 + (size_t)e*512 + i8*8);
    float4 a = s[0], b = s[1];
    uint4 o;
    o.x = pack2(a.x, a.y); o.y = pack2(a.z, a.w);
    o.z = pack2(b.x, b.y); o.w = pack2(b.z, b.w);
    *(uint4*)(Wep + (size_t)e*1536 + (size_t)l*512 + i8*8) = o;
}

// -------- gates: g[l] = sigmoid(x_row . Wg[l]) fp32; u = bf16(x * g[chunk]) -----
// one wave per row; lane covers 6 float4 (24 floats) of the 1536-float row.
__global__ __launch_bounds__(256) void gate_u(const float* __restrict__ x,
                                              const float* __restrict__ Wg,
                                              unsigned short* __restrict__ u)
{
    int row  = blockIdx.x*4 + (threadIdx.x>>6);
    int lane = threadIdx.x & 63;
    const float4* xr = (const float4*)(x + (size_t)row*1536);
    float4 hv[6];
    #pragma unroll
    for(int j=0;j<6;j++) hv[j] = xr[j*64 + lane];

    float p[3];
    #pragma unroll
    for(int l=0;l<3;l++){
        const float4* wr = (const float4*)(Wg + (size_t)l*1536);
        float s = 0.f;
        #pragma unroll
        for(int j=0;j<6;j++){
            float4 wv = wr[j*64 + lane];
            s += hv[j].x*wv.x + hv[j].y*wv.y + hv[j].z*wv.z + hv[j].w*wv.w;
        }
        p[l] = s;
    }
    #pragma unroll
    for(int off=32; off; off>>=1){
        p[0] += __shfl_xor(p[0], off);
        p[1] += __shfl_xor(p[1], off);
        p[2] += __shfl_xor(p[2], off);
    }
    float g[3];
    #pragma unroll
    for(int l=0;l<3;l++) g[l] = 1.f/(1.f + __expf(-p[l]));

    // float4 index f=j*64+lane covers floats [4f,4f+4) -> chunk = f>>7 (same for all 4)
    uint2* ur = (uint2*)(u + (size_t)row*1536);
    #pragma unroll
    for(int j=0;j<6;j++){
        float gj = g[(j*64+lane)>>7];
        uint2 o;
        o.x = pack2(hv[j].x*gj, hv[j].y*gj);
        o.y = pack2(hv[j].z*gj, hv[j].w*gj);
        ur[j*64 + lane] = o;
    }
}

// ---- GEMM: C[M,N] = act(A[M,K] @ W[N,K]^T + bias)  (bf16 in, fp32 acc) ----
// 128x128 tile, BK=32, 4 waves x (4x4) mfma_f32_16x16x32_bf16.
// ACT: 0=none, 1=relu, 2=tanh. BIAS_ROWS fp32 bias rows (stride N) summed.
// F32OUT: store fp32 (final GEMM -> d_out) else bf16 (intermediates).
template<int ACT, int BIAS_ROWS, bool F32OUT>
__global__ __launch_bounds__(256) void gemm_bt(
    const unsigned short* __restrict__ A,
    const unsigned short* __restrict__ W,
    const float* __restrict__ bias,
    void* __restrict__ Cv,
    int M, int N, int K)
{
    __shared__ unsigned short As[128*40];   // +8 pad: row stride 80 B
    __shared__ unsigned short Bs[128*40];

    int tid = threadIdx.x;
    int nb  = N >> 7;
    int bm  = blockIdx.x / nb;
    int bn  = blockIdx.x % nb;
    int m0  = bm << 7, n0 = bn << 7;
    int lane = tid & 63, wvi = tid >> 6;
    int wm = wvi >> 1, wn = wvi & 1;
    int lr = lane & 15, quad = lane >> 4;

    float4v acc[4][4];
    #pragma unroll
    for(int i=0;i<4;i++)
        #pragma unroll
        for(int j=0;j<4;j++) acc[i][j] = (float4v){0.f,0.f,0.f,0.f};

    const unsigned short* Ab = A + (size_t)m0*K;
    const unsigned short* Wb = W + (size_t)n0*K;

    for(int k0=0; k0<K; k0+=32){
        #pragma unroll
        for(int h=0; h<2; h++){
            int v  = tid + h*256;      // 512 vectors of 8 elems per 128x32 tile
            int r  = v >> 2;
            int c8 = (v & 3) * 8;
            uint4 av = *(const uint4*)(Ab + (size_t)r*K + k0 + c8);
            uint4 bv = *(const uint4*)(Wb + (size_t)r*K + k0 + c8);
            *(uint4*)(&As[r*40 + c8]) = av;
            *(uint4*)(&Bs[r*40 + c8]) = bv;
        }
        __syncthreads();

        short8 af[4], bfr[4];
        #pragma unroll
        for(int mi=0;mi<4;mi++)
            af[mi] = *(const short8*)(&As[(wm*64 + mi*16 + lr)*40 + quad*8]);
        #pragma unroll
        for(int ni=0;ni<4;ni++)
            bfr[ni] = *(const short8*)(&Bs[(wn*64 + ni*16 + lr)*40 + quad*8]);

        #pragma unroll
        for(int mi=0;mi<4;mi++)
            #pragma unroll
            for(int ni=0;ni<4;ni++)
                acc[mi][ni] = __builtin_amdgcn_mfma_f32_16x16x32_bf16(af[mi], bfr[ni], acc[mi][ni], 0, 0, 0);
        __syncthreads();
    }

    // epilogue: C/D layout col(n)=lane&15, row(m)=quad*4+reg (m89/m91-verified)
    #pragma unroll
    for(int ni=0;ni<4;ni++){
        int n = n0 + wn*64 + ni*16 + lr;
        float bsum = 0.f;
        #pragma unroll
        for(int r=0;r<BIAS_ROWS;r++) bsum += bias[(size_t)r*N + n];
        #pragma unroll
        for(int mi=0;mi<4;mi++){
            #pragma unroll
            for(int reg=0;reg<4;reg++){
                int m = m0 + wm*64 + mi*16 + quad*4 + reg;
                float v = acc[mi][ni][reg] + bsum;
                if(ACT==1)      v = fmaxf(v, 0.f);
                else if(ACT==2) v = tanhf(v);
                if constexpr (F32OUT) ((float*)Cv)[(size_t)m*N + n] = v;
                else                  ((unsigned short*)Cv)[(size_t)m*N + n] = f2bf(v);
            }
        }
    }
}

extern "C" void kernel_launch(void* const* d_in, const int* in_sizes, int n_in,
                              void* d_out, int out_size, void* d_ws, size_t ws_size,
                              hipStream_t stream)
{
    const float* x  = (const float*)d_in[0];
    const float* Wg = (const float*)d_in[1];
    const float* We = (const float*)d_in[2];
    const float* be = (const float*)d_in[3];
    const float* W1 = (const float*)d_in[4];
    const float* b1 = (const float*)d_in[5];
    const float* W2 = (const float*)d_in[6];
    const float* b2 = (const float*)d_in[7];
    const float* Wo = (const float*)d_in[8];
    const float* bo = (const float*)d_in[9];
    float* out = (float*)d_out;

    const int MC = 16384;     // chunk rows; 2 chunks of B*T=32768

    // workspace: 3+2+2+1 weights + 48 slotA + 32 slotB = 88 MB
    char* w = (char*)d_ws;
    unsigned short* Wep   = (unsigned short*)w; w += (size_t)1024*1536*2;  //  3 MB
    unsigned short* W1b   = (unsigned short*)w; w += (size_t)1024*1024*2;  //  2 MB
    unsigned short* W2b   = (unsigned short*)w; w += (size_t)1024*1024*2;  //  2 MB
    unsigned short* Wob   = (unsigned short*)w; w += (size_t)512*1024*2;   //  1 MB
    unsigned short* slotA = (unsigned short*)w; w += (size_t)MC*1536*2;    // 48 MB
    unsigned short* slotB = (unsigned short*)w; w += (size_t)MC*1024*2;    // 32 MB
    unsigned short* u  = slotA;   // [MC,1536]
    unsigned short* o1 = slotA;   // [MC,1024] (u dead after GEMM-1)
    unsigned short* he = slotB;   // [MC,1024]
    unsigned short* o2 = slotB;   // [MC,1024] (he dead after GEMM-2)

    hipLaunchKernelGGL(cvt_flat, dim3(512), dim3(256), 0, stream, W1, W1b, 131072);
    hipLaunchKernelGGL(cvt_flat, dim3(512), dim3(256), 0, stream, W2, W2b, 131072);
    hipLaunchKernelGGL(cvt_flat, dim3(256), dim3(256), 0, stream, Wo, Wob, 65536);
    hipLaunchKernelGGL(cvt_we,   dim3(768), dim3(256), 0, stream, We, Wep);

    for(int c=0; c<2; c++){
        const float* xc = x   + (size_t)c*MC*1536;
        float* outc     = out + (size_t)c*MC*512;

        hipLaunchKernelGGL(gate_u, dim3(MC/4), dim3(256), 0, stream, xc, Wg, u);
        hipLaunchKernelGGL((gemm_bt<1,3,false>), dim3((MC/128)*(1024/128)), dim3(256), 0, stream,
                           u,  Wep, be, he,   MC, 1024, 1536);
        hipLaunchKernelGGL((gemm_bt<2,1,false>), dim3((MC/128)*(1024/128)), dim3(256), 0, stream,
                           he, W1b, b1, o1,   MC, 1024, 1024);
        hipLaunchKernelGGL((gemm_bt<2,1,false>), dim3((MC/128)*(1024/128)), dim3(256), 0, stream,
                           o1, W2b, b2, o2,   MC, 1024, 1024);
        hipLaunchKernelGGL((gemm_bt<0,1,true>),  dim3((MC/128)*(512/128)),  dim3(256), 0, stream,
                           o2, Wob, bo, outc, MC, 512, 1024);
    }
}

// Round 5
// 777.552 us; speedup vs baseline: 1.1417x; 1.1417x over previous
//
#include <hip/hip_runtime.h>
#include <math.h>

// HMLSTMOutput — fp32 in / fp32 out buffers; internal bf16 MFMA compute (2% tol vs bf16 ref).
// R5: m97-style GEMM staging (global_load_lds width=16, unpadded LDS) + single-chunk
// schedule (ws ~168 MB; harness poison fill showed ws_size ~768 MB).

typedef __attribute__((ext_vector_type(8))) short short8;   // 8 bf16 = 4 VGPRs (MFMA A/B frag)
typedef __attribute__((ext_vector_type(4))) float float4v;  // MFMA C/D frag

#define DEV __device__ __forceinline__

DEV unsigned short f2bf(float f){
    union{float f; unsigned int i;} c; c.f = f;
    unsigned int r = c.i + 0x7fffu + ((c.i>>16)&1u);   // round-to-nearest-even
    return (unsigned short)(r>>16);
}
DEV unsigned int pack2(float a, float b){
    return (unsigned int)f2bf(a) | ((unsigned int)f2bf(b)<<16);
}

// direct global->LDS DMA, 16 B per lane; LDS dest = wave-uniform base + lane*16 (m104/m108)
DEV void gload_lds16(const unsigned short* g, unsigned short* l){
    __builtin_amdgcn_global_load_lds((const __attribute__((address_space(1))) void*)g,
                                     (__attribute__((address_space(3))) void*)l, 16, 0, 0);
}

// -------- convert fp32 -> bf16, flat (W1, W2, Wo). 8 elems / thread ----------
__global__ __launch_bounds__(256) void cvt_flat(const float* __restrict__ src,
                                                unsigned short* __restrict__ dst, int n8)
{
    int v = blockIdx.x*256 + threadIdx.x;
    if(v >= n8) return;
    const float4* s = (const float4*)(src) + v*2;
    float4 a = s[0], b = s[1];
    uint4 o;
    o.x = pack2(a.x, a.y); o.y = pack2(a.z, a.w);
    o.z = pack2(b.x, b.y); o.w = pack2(b.z, b.w);
    *((uint4*)dst + v) = o;
}

// -------- We [3,1024,512] fp32 -> Wep [1024,1536] bf16 (repack + convert) -------
__global__ __launch_bounds__(256) void cvt_we(const float* __restrict__ We,
                                              unsigned short* __restrict__ Wep)
{
    int v  = blockIdx.x*256 + threadIdx.x;   // 196608 vectors of 8 elems
    int i8 = v & 63;
    int e  = (v>>6) & 1023;
    int l  = v>>16;
    const float4* s = (const float4*)(We + (size_t)l*524288 + (size_t)e*512 + i8*8);
    float4 a = s[0], b = s[1];
    uint4 o;
    o.x = pack2(a.x, a.y); o.y = pack2(a.z, a.w);
    o.z = pack2(b.x, b.y); o.w = pack2(b.z, b.w);
    *(uint4*)(Wep + (size_t)e*1536 + (size_t)l*512 + i8*8) = o;
}

// -------- gates: g[l] = sigmoid(x_row . Wg[l]) fp32; u = bf16(x * g[chunk]) -----
__global__ __launch_bounds__(256) void gate_u(const float* __restrict__ x,
                                              const float* __restrict__ Wg,
                                              unsigned short* __restrict__ u)
{
    int row  = blockIdx.x*4 + (threadIdx.x>>6);
    int lane = threadIdx.x & 63;
    const float4* xr = (const float4*)(x + (size_t)row*1536);
    float4 hv[6];
    #pragma unroll
    for(int j=0;j<6;j++) hv[j] = xr[j*64 + lane];

    float p[3];
    #pragma unroll
    for(int l=0;l<3;l++){
        const float4* wr = (const float4*)(Wg + (size_t)l*1536);
        float s = 0.f;
        #pragma unroll
        for(int j=0;j<6;j++){
            float4 wv = wr[j*64 + lane];
            s += hv[j].x*wv.x + hv[j].y*wv.y + hv[j].z*wv.z + hv[j].w*wv.w;
        }
        p[l] = s;
    }
    #pragma unroll
    for(int off=32; off; off>>=1){
        p[0] += __shfl_xor(p[0], off);
        p[1] += __shfl_xor(p[1], off);
        p[2] += __shfl_xor(p[2], off);
    }
    float g[3];
    #pragma unroll
    for(int l=0;l<3;l++) g[l] = 1.f/(1.f + __expf(-p[l]));

    uint2* ur = (uint2*)(u + (size_t)row*1536);
    #pragma unroll
    for(int j=0;j<6;j++){
        float gj = g[(j*64+lane)>>7];   // float4 f=j*64+lane covers [4f,4f+4) -> chunk f>>7
        uint2 o;
        o.x = pack2(hv[j].x*gj, hv[j].y*gj);
        o.y = pack2(hv[j].z*gj, hv[j].w*gj);
        ur[j*64 + lane] = o;
    }
}

// ---- GEMM: C[M,N] = act(A[M,K] @ W[N,K]^T + bias)  (bf16 in, fp32 acc) ----
// m97 structure: 128x128 tile, BK=32, global_load_lds width=16 staging into UNPADDED
// LDS (row stride 64 B — DMA layout is lane-ordered, padding would corrupt it),
// 4 waves x (4x4) mfma_f32_16x16x32_bf16.
template<int ACT, int BIAS_ROWS, bool F32OUT>
__global__ __launch_bounds__(256) void gemm_bt(
    const unsigned short* __restrict__ A,
    const unsigned short* __restrict__ W,
    const float* __restrict__ bias,
    void* __restrict__ Cv,
    int M, int N, int K)
{
    __shared__ __align__(128) unsigned short As[128*32];   // 8 KB, no pad
    __shared__ __align__(128) unsigned short Bs[128*32];

    int tid = threadIdx.x;
    int nb  = N >> 7;
    int bm  = blockIdx.x / nb;
    int bn  = blockIdx.x % nb;
    int m0  = bm << 7, n0 = bn << 7;
    int lane = tid & 63, wv = tid >> 6;
    int wm = wv >> 1, wn = wv & 1;
    int lr = lane & 15, quad = lane >> 4;

    float4v acc[4][4];
    #pragma unroll
    for(int i=0;i<4;i++)
        #pragma unroll
        for(int j=0;j<4;j++) acc[i][j] = (float4v){0.f,0.f,0.f,0.f};

    // staging: wave wv covers rows [wv*32, wv*32+32) of each tile as two 16-row DMAs.
    // lane i: row += i/4, col-block (i&3)*8 elems (16 B) -> LDS byte offset i*16. exact match.
    const unsigned short* gA = A + ((size_t)m0 + wv*32 + (lane>>2))*K + (lane&3)*8;
    const unsigned short* gB = W + ((size_t)n0 + wv*32 + (lane>>2))*K + (lane&3)*8;
    unsigned short* lA0 = &As[(wv*32)*32];        // wave-uniform bases
    unsigned short* lA1 = &As[(wv*32+16)*32];
    unsigned short* lB0 = &Bs[(wv*32)*32];
    unsigned short* lB1 = &Bs[(wv*32+16)*32];
    const size_t rstep = (size_t)16*K;

    for(int k0=0; k0<K; k0+=32){
        gload_lds16(gA,         lA0);
        gload_lds16(gA + rstep, lA1);
        gload_lds16(gB,         lB0);
        gload_lds16(gB + rstep, lB1);
        gA += 32; gB += 32;
        __syncthreads();   // drains vmcnt(0) then barrier: tiles complete for all waves

        short8 af[4], bfr[4];
        #pragma unroll
        for(int mi=0;mi<4;mi++)
            af[mi] = *(const short8*)(&As[(wm*64 + mi*16 + lr)*32 + quad*8]);
        #pragma unroll
        for(int ni=0;ni<4;ni++)
            bfr[ni] = *(const short8*)(&Bs[(wn*64 + ni*16 + lr)*32 + quad*8]);

        #pragma unroll
        for(int mi=0;mi<4;mi++)
            #pragma unroll
            for(int ni=0;ni<4;ni++)
                acc[mi][ni] = __builtin_amdgcn_mfma_f32_16x16x32_bf16(af[mi], bfr[ni], acc[mi][ni], 0, 0, 0);
        __syncthreads();   // protect LDS before next k-step's DMA overwrite
    }

    // epilogue: C/D layout col(n)=lane&15, row(m)=quad*4+reg (m89/m91-verified)
    #pragma unroll
    for(int ni=0;ni<4;ni++){
        int n = n0 + wn*64 + ni*16 + lr;
        float bsum = 0.f;
        #pragma unroll
        for(int r=0;r<BIAS_ROWS;r++) bsum += bias[(size_t)r*N + n];
        #pragma unroll
        for(int mi=0;mi<4;mi++){
            #pragma unroll
            for(int reg=0;reg<4;reg++){
                int m = m0 + wm*64 + mi*16 + quad*4 + reg;
                float v = acc[mi][ni][reg] + bsum;
                if(ACT==1)      v = fmaxf(v, 0.f);
                else if(ACT==2) v = tanhf(v);
                if constexpr (F32OUT) ((float*)Cv)[(size_t)m*N + n] = v;
                else                  ((unsigned short*)Cv)[(size_t)m*N + n] = f2bf(v);
            }
        }
    }
}

extern "C" void kernel_launch(void* const* d_in, const int* in_sizes, int n_in,
                              void* d_out, int out_size, void* d_ws, size_t ws_size,
                              hipStream_t stream)
{
    const float* x  = (const float*)d_in[0];
    const float* Wg = (const float*)d_in[1];
    const float* We = (const float*)d_in[2];
    const float* be = (const float*)d_in[3];
    const float* W1 = (const float*)d_in[4];
    const float* b1 = (const float*)d_in[5];
    const float* W2 = (const float*)d_in[6];
    const float* b2 = (const float*)d_in[7];
    const float* Wo = (const float*)d_in[8];
    const float* bo = (const float*)d_in[9];
    float* out = (float*)d_out;

    const int M = 32768;    // B*T, single chunk (ws_size ~768 MB per harness fill)

    // workspace: 8 MB weights + 96 MB slotA + 64 MB slotB = 168 MB
    char* w = (char*)d_ws;
    unsigned short* Wep   = (unsigned short*)w; w += (size_t)1024*1536*2;  //  3 MB
    unsigned short* W1b   = (unsigned short*)w; w += (size_t)1024*1024*2;  //  2 MB
    unsigned short* W2b   = (unsigned short*)w; w += (size_t)1024*1024*2;  //  2 MB
    unsigned short* Wob   = (unsigned short*)w; w += (size_t)512*1024*2;   //  1 MB
    unsigned short* slotA = (unsigned short*)w; w += (size_t)M*1536*2;     // 96 MB
    unsigned short* slotB = (unsigned short*)w; w += (size_t)M*1024*2;     // 64 MB
    unsigned short* u  = slotA;   // [M,1536]
    unsigned short* o1 = slotA;   // [M,1024] (u dead after GEMM-1)
    unsigned short* he = slotB;   // [M,1024]
    unsigned short* o2 = slotB;   // [M,1024] (he dead after GEMM-2)

    hipLaunchKernelGGL(cvt_flat, dim3(512), dim3(256), 0, stream, W1, W1b, 131072);
    hipLaunchKernelGGL(cvt_flat, dim3(512), dim3(256), 0, stream, W2, W2b, 131072);
    hipLaunchKernelGGL(cvt_flat, dim3(256), dim3(256), 0, stream, Wo, Wob, 65536);
    hipLaunchKernelGGL(cvt_we,   dim3(768), dim3(256), 0, stream, We, Wep);

    hipLaunchKernelGGL(gate_u, dim3(M/4), dim3(256), 0, stream, x, Wg, u);
    hipLaunchKernelGGL((gemm_bt<1,3,false>), dim3((M/128)*(1024/128)), dim3(256), 0, stream,
                       u,  Wep, be, he,  M, 1024, 1536);
    hipLaunchKernelGGL((gemm_bt<2,1,false>), dim3((M/128)*(1024/128)), dim3(256), 0, stream,
                       he, W1b, b1, o1,  M, 1024, 1024);
    hipLaunchKernelGGL((gemm_bt<2,1,false>), dim3((M/128)*(1024/128)), dim3(256), 0, stream,
                       o1, W2b, b2, o2,  M, 1024, 1024);
    hipLaunchKernelGGL((gemm_bt<0,1,true>),  dim3((M/128)*(512/128)),  dim3(256), 0, stream,
                       o2, Wob, bo, out, M, 512, 1024);
}

// Round 6
// 733.405 us; speedup vs baseline: 1.2104x; 1.0602x over previous
//
#include <hip/hip_runtime.h>
#include <math.h>

// HMLSTMOutput — fp32 in/out buffers; internal bf16 MFMA (2% tol vs bf16-computed ref).
// R6: (a) XCD-aware block swizzle: each XCD (blockIdx&7) owns an exclusive bm-range so
//     A-tiles + the 3MB weight matrix stay hot in that XCD's private L2 (R5 showed 398MB
//     HBM fetch vs 99MB ideal = cross-XCD A re-fetch).
// (b) BK=64 with XOR-swizzled global_load_lds staging: LDS slot r*8+(cb^(r&7)) makes the
//     b128 fragment reads 2-way bank-conflict-free (R5: 1.26e7 conflicts, 8-way) and
//     halves the vmcnt(0)+barrier drains per K-loop.

typedef __attribute__((ext_vector_type(8))) short short8;   // 8 bf16 = 4 VGPRs (MFMA A/B frag)
typedef __attribute__((ext_vector_type(4))) float float4v;  // MFMA C/D frag

#define DEV __device__ __forceinline__

DEV unsigned short f2bf(float f){
    union{float f; unsigned int i;} c; c.f = f;
    unsigned int r = c.i + 0x7fffu + ((c.i>>16)&1u);   // round-to-nearest-even
    return (unsigned short)(r>>16);
}
DEV unsigned int pack2(float a, float b){
    return (unsigned int)f2bf(a) | ((unsigned int)f2bf(b)<<16);
}

// direct global->LDS DMA, 16 B per lane; LDS dest = wave-uniform base + lane*16
DEV void gload_lds16(const unsigned short* g, unsigned short* l){
    __builtin_amdgcn_global_load_lds((const __attribute__((address_space(1))) void*)g,
                                     (__attribute__((address_space(3))) void*)l, 16, 0, 0);
}

// -------- convert fp32 -> bf16, flat (W1, W2, Wo). 8 elems / thread ----------
__global__ __launch_bounds__(256) void cvt_flat(const float* __restrict__ src,
                                                unsigned short* __restrict__ dst, int n8)
{
    int v = blockIdx.x*256 + threadIdx.x;
    if(v >= n8) return;
    const float4* s = (const float4*)(src) + v*2;
    float4 a = s[0], b = s[1];
    uint4 o;
    o.x = pack2(a.x, a.y); o.y = pack2(a.z, a.w);
    o.z = pack2(b.x, b.y); o.w = pack2(b.z, b.w);
    *((uint4*)dst + v) = o;
}

// -------- We [3,1024,512] fp32 -> Wep [1024,1536] bf16 (repack + convert) -------
__global__ __launch_bounds__(256) void cvt_we(const float* __restrict__ We,
                                              unsigned short* __restrict__ Wep)
{
    int v  = blockIdx.x*256 + threadIdx.x;   // 196608 vectors of 8 elems
    int i8 = v & 63;
    int e  = (v>>6) & 1023;
    int l  = v>>16;
    const float4* s = (const float4*)(We + (size_t)l*524288 + (size_t)e*512 + i8*8);
    float4 a = s[0], b = s[1];
    uint4 o;
    o.x = pack2(a.x, a.y); o.y = pack2(a.z, a.w);
    o.z = pack2(b.x, b.y); o.w = pack2(b.z, b.w);
    *(uint4*)(Wep + (size_t)e*1536 + (size_t)l*512 + i8*8) = o;
}

// -------- gates: g[l] = sigmoid(x_row . Wg[l]) fp32; u = bf16(x * g[chunk]) -----
__global__ __launch_bounds__(256) void gate_u(const float* __restrict__ x,
                                              const float* __restrict__ Wg,
                                              unsigned short* __restrict__ u)
{
    int row  = blockIdx.x*4 + (threadIdx.x>>6);
    int lane = threadIdx.x & 63;
    const float4* xr = (const float4*)(x + (size_t)row*1536);
    float4 hv[6];
    #pragma unroll
    for(int j=0;j<6;j++) hv[j] = xr[j*64 + lane];

    float p[3];
    #pragma unroll
    for(int l=0;l<3;l++){
        const float4* wr = (const float4*)(Wg + (size_t)l*1536);
        float s = 0.f;
        #pragma unroll
        for(int j=0;j<6;j++){
            float4 wv = wr[j*64 + lane];
            s += hv[j].x*wv.x + hv[j].y*wv.y + hv[j].z*wv.z + hv[j].w*wv.w;
        }
        p[l] = s;
    }
    #pragma unroll
    for(int off=32; off; off>>=1){
        p[0] += __shfl_xor(p[0], off);
        p[1] += __shfl_xor(p[1], off);
        p[2] += __shfl_xor(p[2], off);
    }
    float g[3];
    #pragma unroll
    for(int l=0;l<3;l++) g[l] = 1.f/(1.f + __expf(-p[l]));

    uint2* ur = (uint2*)(u + (size_t)row*1536);
    #pragma unroll
    for(int j=0;j<6;j++){
        float gj = g[(j*64+lane)>>7];   // float4 f=j*64+lane covers [4f,4f+4) -> chunk f>>7
        uint2 o;
        o.x = pack2(hv[j].x*gj, hv[j].y*gj);
        o.y = pack2(hv[j].z*gj, hv[j].w*gj);
        ur[j*64 + lane] = o;
    }
}

// ---- GEMM: C[M,N] = act(A[M,K] @ W[N,K]^T + bias)  (bf16 in, fp32 acc) ----
// 128x128 tile, BK=64, XOR-swizzled global_load_lds staging, 4 waves x (4x4)
// mfma_f32_16x16x32_bf16 (two k-substeps per K-iter). XCD-swizzled block mapping.
template<int ACT, int BIAS_ROWS, bool F32OUT>
__global__ __launch_bounds__(256) void gemm_bt(
    const unsigned short* __restrict__ A,
    const unsigned short* __restrict__ W,
    const float* __restrict__ bias,
    void* __restrict__ Cv,
    int M, int N, int K)
{
    __shared__ __align__(128) unsigned short As[128*64];   // 16 KB, swizzled slots
    __shared__ __align__(128) unsigned short Bs[128*64];

    int tid = threadIdx.x;
    int nb  = N >> 7;            // n-tiles
    int mt  = M >> 7;            // m-tiles (divisible by 8)
    // XCD swizzle: xcd = blockIdx&7 owns bm in [xcd*mt/8, (xcd+1)*mt/8); bn cycles fastest
    int xcd = blockIdx.x & 7;
    int j   = blockIdx.x >> 3;
    int bm  = xcd*(mt>>3) + j/nb;
    int bn  = j % nb;
    int m0  = bm << 7, n0 = bn << 7;

    int lane = tid & 63, wv = tid >> 6;
    int wm = wv >> 1, wn = wv & 1;
    int lr = lane & 15, quad = lane >> 4;

    float4v acc[4][4];
    #pragma unroll
    for(int i=0;i<4;i++)
        #pragma unroll
        for(int jj=0;jj<4;jj++) acc[i][jj] = (float4v){0.f,0.f,0.f,0.f};

    // staging: wave wv covers rows [wv*32, wv*32+32) as 4 DMAs of 8 rows.
    // lane i: local row rl=i>>3, 16B-block cb = (i&7)^rl  (XOR swizzle).
    // LDS slot of tile elem (r, cb) = r*8 + (cb ^ (r&7))  -> frag reads 2-way free.
    int rl  = lane >> 3;
    int cbs = (lane & 7) ^ rl;
    const unsigned short* gA = A + ((size_t)m0 + wv*32 + rl)*K + cbs*8;
    const unsigned short* gB = W + ((size_t)n0 + wv*32 + rl)*K + cbs*8;
    const size_t rstep = (size_t)8*K;

    for(int k0=0; k0<K; k0+=64){
        #pragma unroll
        for(int d=0; d<4; d++){
            gload_lds16(gA + d*rstep, &As[(wv*32 + d*8)*64]);
            gload_lds16(gB + d*rstep, &Bs[(wv*32 + d*8)*64]);
        }
        gA += 64; gB += 64;
        __syncthreads();   // vmcnt(0) drain + barrier: tiles ready

        #pragma unroll
        for(int ks=0; ks<2; ks++){
            short8 af[4], bfr[4];
            #pragma unroll
            for(int mi=0;mi<4;mi++){
                int row = wm*64 + mi*16 + lr;               // row&7 == lr&7
                int cbx = (ks*4 + quad) ^ (lr & 7);
                af[mi] = *(const short8*)(&As[row*64 + cbx*8]);
            }
            #pragma unroll
            for(int ni=0;ni<4;ni++){
                int row = wn*64 + ni*16 + lr;
                int cbx = (ks*4 + quad) ^ (lr & 7);
                bfr[ni] = *(const short8*)(&Bs[row*64 + cbx*8]);
            }
            #pragma unroll
            for(int mi=0;mi<4;mi++)
                #pragma unroll
                for(int ni=0;ni<4;ni++)
                    acc[mi][ni] = __builtin_amdgcn_mfma_f32_16x16x32_bf16(af[mi], bfr[ni], acc[mi][ni], 0, 0, 0);
        }
        __syncthreads();   // protect LDS before next iter's DMA
    }

    // epilogue: C/D layout col(n)=lane&15, row(m)=quad*4+reg (m89/m91-verified)
    #pragma unroll
    for(int ni=0;ni<4;ni++){
        int n = n0 + wn*64 + ni*16 + lr;
        float bsum = 0.f;
        #pragma unroll
        for(int r=0;r<BIAS_ROWS;r++) bsum += bias[(size_t)r*N + n];
        #pragma unroll
        for(int mi=0;mi<4;mi++){
            #pragma unroll
            for(int reg=0;reg<4;reg++){
                int m = m0 + wm*64 + mi*16 + quad*4 + reg;
                float v = acc[mi][ni][reg] + bsum;
                if(ACT==1)      v = fmaxf(v, 0.f);
                else if(ACT==2) v = tanhf(v);
                if constexpr (F32OUT) ((float*)Cv)[(size_t)m*N + n] = v;
                else                  ((unsigned short*)Cv)[(size_t)m*N + n] = f2bf(v);
            }
        }
    }
}

extern "C" void kernel_launch(void* const* d_in, const int* in_sizes, int n_in,
                              void* d_out, int out_size, void* d_ws, size_t ws_size,
                              hipStream_t stream)
{
    const float* x  = (const float*)d_in[0];
    const float* Wg = (const float*)d_in[1];
    const float* We = (const float*)d_in[2];
    const float* be = (const float*)d_in[3];
    const float* W1 = (const float*)d_in[4];
    const float* b1 = (const float*)d_in[5];
    const float* W2 = (const float*)d_in[6];
    const float* b2 = (const float*)d_in[7];
    const float* Wo = (const float*)d_in[8];
    const float* bo = (const float*)d_in[9];
    float* out = (float*)d_out;

    const int M = 32768;    // B*T

    // workspace: 8 MB weights + 96 MB slotA + 64 MB slotB = 168 MB
    char* w = (char*)d_ws;
    unsigned short* Wep   = (unsigned short*)w; w += (size_t)1024*1536*2;  //  3 MB
    unsigned short* W1b   = (unsigned short*)w; w += (size_t)1024*1024*2;  //  2 MB
    unsigned short* W2b   = (unsigned short*)w; w += (size_t)1024*1024*2;  //  2 MB
    unsigned short* Wob   = (unsigned short*)w; w += (size_t)512*1024*2;   //  1 MB
    unsigned short* slotA = (unsigned short*)w; w += (size_t)M*1536*2;     // 96 MB
    unsigned short* slotB = (unsigned short*)w; w += (size_t)M*1024*2;     // 64 MB
    unsigned short* u  = slotA;   // [M,1536]
    unsigned short* o1 = slotA;   // [M,1024] (u dead after GEMM-1)
    unsigned short* he = slotB;   // [M,1024]
    unsigned short* o2 = slotB;   // [M,1024] (he dead after GEMM-2)

    hipLaunchKernelGGL(cvt_flat, dim3(512), dim3(256), 0, stream, W1, W1b, 131072);
    hipLaunchKernelGGL(cvt_flat, dim3(512), dim3(256), 0, stream, W2, W2b, 131072);
    hipLaunchKernelGGL(cvt_flat, dim3(256), dim3(256), 0, stream, Wo, Wob, 65536);
    hipLaunchKernelGGL(cvt_we,   dim3(768), dim3(256), 0, stream, We, Wep);

    hipLaunchKernelGGL(gate_u, dim3(M/4), dim3(256), 0, stream, x, Wg, u);
    hipLaunchKernelGGL((gemm_bt<1,3,false>), dim3((M/128)*(1024/128)), dim3(256), 0, stream,
                       u,  Wep, be, he,  M, 1024, 1536);
    hipLaunchKernelGGL((gemm_bt<2,1,false>), dim3((M/128)*(1024/128)), dim3(256), 0, stream,
                       he, W1b, b1, o1,  M, 1024, 1024);
    hipLaunchKernelGGL((gemm_bt<2,1,false>), dim3((M/128)*(1024/128)), dim3(256), 0, stream,
                       o1, W2b, b2, o2,  M, 1024, 1024);
    hipLaunchKernelGGL((gemm_bt<0,1,true>),  dim3((M/128)*(512/128)),  dim3(256), 0, stream,
                       o2, Wob, bo, out, M, 512, 1024);
}